// Round 7
// baseline (101.818 us; speedup 1.0000x reference)
//
#include <hip/hip_runtime.h>

// B=32, T=2048, D=1024 (fp32)
// out[b,d] = sum_t softmax_t(tanh(x[b,t,:]·W + bias[t])) * x[b,t,d]
// tanh in (-1,1) -> exp never overflows -> single pass, no max subtraction.
//
// R7: R6 structure (no fences/tickets - 5x poison in R3/R4), with:
//  - 3-row-deep register prefetch (4-slot rotation, compile-time indices only,
//    __launch_bounds__(256,4) pins VGPR<=128 so occupancy stays 4 waves/SIMD)
//  - combine kernel unrolled x8

#define PSTR 1032  // floats per partial: [0]=lsum, [8..1032)=acc[1024]

__global__ __launch_bounds__(256, 4) void fused_main(
    const float* __restrict__ x, const float* __restrict__ w,
    const float* __restrict__ bias, float* __restrict__ partials,
    int T, int C)
{
    const int c = blockIdx.x;      // T-chunk (64 rows)
    const int b = blockIdx.y;      // batch
    const int wv = threadIdx.x >> 6;
    const int lane = threadIdx.x & 63;
    const int tid = threadIdx.x;

    const int rows_block = T / C;              // 64
    const int rows_wave  = rows_block >> 2;    // 16
    const int r0 = c * rows_block + wv * rows_wave;

    // W fragment: lane l holds w[k*256 + l*4 .. +3]
    const float4* w4 = (const float4*)w;
    const float4 wf0 = w4[lane];
    const float4 wf1 = w4[lane + 64];
    const float4 wf2 = w4[lane + 128];
    const float4 wf3 = w4[lane + 192];

    // bias for this wave's 16 rows, one per lane
    float biasv = (lane < rows_wave) ? bias[r0 + lane] : 0.f;

    const float4* xr0 = (const float4*)x + ((size_t)b * T + r0) * 256 + lane;

    float4 acc0 = {0,0,0,0}, acc1 = {0,0,0,0}, acc2 = {0,0,0,0}, acc3 = {0,0,0,0};
    float lsum = 0.f;

    float4 buf[4][4];  // 4-slot rotation; indexed ONLY by constants after unroll

#define LOADG(gg) do {                                   \
    const float4* _p = xr0 + (size_t)(gg) * 256;         \
    buf[(gg) & 3][0] = _p[0];                            \
    buf[(gg) & 3][1] = _p[64];                           \
    buf[(gg) & 3][2] = _p[128];                          \
    buf[(gg) & 3][3] = _p[192];                          \
} while (0)

#define COMPUTEG(gg) do {                                                     \
    float4 a0 = buf[(gg) & 3][0], a1 = buf[(gg) & 3][1];                      \
    float4 a2 = buf[(gg) & 3][2], a3 = buf[(gg) & 3][3];                      \
    float d = a0.x*wf0.x + a0.y*wf0.y + a0.z*wf0.z + a0.w*wf0.w;              \
    d += a1.x*wf1.x + a1.y*wf1.y + a1.z*wf1.z + a1.w*wf1.w;                   \
    d += a2.x*wf2.x + a2.y*wf2.y + a2.z*wf2.z + a2.w*wf2.w;                   \
    d += a3.x*wf3.x + a3.y*wf3.y + a3.z*wf3.z + a3.w*wf3.w;                   \
    _Pragma("unroll")                                                         \
    for (int off = 1; off < 64; off <<= 1) d += __shfl_xor(d, off);           \
    float _a = d + __shfl(biasv, (gg));                                       \
    float _t = 1.f - 2.f / (__expf(2.f * _a) + 1.f);   /* tanh, inf-safe */   \
    float e = __expf(_t);                                                     \
    lsum += e;                                                                \
    acc0.x += e*a0.x; acc0.y += e*a0.y; acc0.z += e*a0.z; acc0.w += e*a0.w;   \
    acc1.x += e*a1.x; acc1.y += e*a1.y; acc1.z += e*a1.z; acc1.w += e*a1.w;   \
    acc2.x += e*a2.x; acc2.y += e*a2.y; acc2.z += e*a2.z; acc2.w += e*a2.w;   \
    acc3.x += e*a3.x; acc3.y += e*a3.y; acc3.z += e*a3.z; acc3.w += e*a3.w;   \
} while (0)

    LOADG(0);
    LOADG(1);
    LOADG(2);
#pragma unroll
    for (int g = 0; g < 16; ++g) {   // rows_wave == 16 (host guarantees)
        if (g < 13) LOADG(g + 3);    // three rows always in flight during compute
        COMPUTEG(g);
    }

#undef LOADG
#undef COMPUTEG

    // combine 4 waves via LDS -> one partial per block
    __shared__ float lacc[4 * 1024];
    __shared__ float lls[4];
    float4* lacc4 = (float4*)lacc;
    lacc4[wv * 256 + lane]       = acc0;
    lacc4[wv * 256 + 64 + lane]  = acc1;
    lacc4[wv * 256 + 128 + lane] = acc2;
    lacc4[wv * 256 + 192 + lane] = acc3;
    if (lane == 0) lls[wv] = lsum;
    __syncthreads();

    float4 o0 = lacc4[tid];
    float4 o1 = lacc4[256 + tid];
    float4 o2 = lacc4[512 + tid];
    float4 o3 = lacc4[768 + tid];
    float4 o;
    o.x = (o0.x + o1.x) + (o2.x + o3.x);
    o.y = (o0.y + o1.y) + (o2.y + o3.y);
    o.z = (o0.z + o1.z) + (o2.z + o3.z);
    o.w = (o0.w + o1.w) + (o2.w + o3.w);

    float* p = partials + (size_t)(b * C + c) * PSTR;
    if (tid == 0) p[0] = (lls[0] + lls[1]) + (lls[2] + lls[3]);
    ((float4*)(p + 8))[tid] = o;
}

__global__ __launch_bounds__(256) void combine_kernel(
    const float* __restrict__ partials, float* __restrict__ out, int C)
{
    const int b = blockIdx.x;
    const int tid = threadIdx.x;

    float L = 0.f;
    float4 oA = {0,0,0,0}, oB = {0,0,0,0}, oC = {0,0,0,0}, oD = {0,0,0,0};
    float4 oE = {0,0,0,0}, oF = {0,0,0,0}, oG = {0,0,0,0}, oH = {0,0,0,0};

    int c = 0;
    for (; c + 8 <= C; c += 8) {
        const float* p0 = partials + (size_t)(b * C + c) * PSTR;
        float l0 = p0[0], l1 = p0[PSTR], l2 = p0[2*PSTR], l3 = p0[3*PSTR];
        float l4 = p0[4*PSTR], l5 = p0[5*PSTR], l6 = p0[6*PSTR], l7 = p0[7*PSTR];
        float4 a0 = ((const float4*)(p0 + 8))[tid];
        float4 a1 = ((const float4*)(p0 + PSTR + 8))[tid];
        float4 a2 = ((const float4*)(p0 + 2*PSTR + 8))[tid];
        float4 a3 = ((const float4*)(p0 + 3*PSTR + 8))[tid];
        float4 a4 = ((const float4*)(p0 + 4*PSTR + 8))[tid];
        float4 a5 = ((const float4*)(p0 + 5*PSTR + 8))[tid];
        float4 a6 = ((const float4*)(p0 + 6*PSTR + 8))[tid];
        float4 a7 = ((const float4*)(p0 + 7*PSTR + 8))[tid];
        L += ((l0 + l1) + (l2 + l3)) + ((l4 + l5) + (l6 + l7));
        oA.x += a0.x; oA.y += a0.y; oA.z += a0.z; oA.w += a0.w;
        oB.x += a1.x; oB.y += a1.y; oB.z += a1.z; oB.w += a1.w;
        oC.x += a2.x; oC.y += a2.y; oC.z += a2.z; oC.w += a2.w;
        oD.x += a3.x; oD.y += a3.y; oD.z += a3.z; oD.w += a3.w;
        oE.x += a4.x; oE.y += a4.y; oE.z += a4.z; oE.w += a4.w;
        oF.x += a5.x; oF.y += a5.y; oF.z += a5.z; oF.w += a5.w;
        oG.x += a6.x; oG.y += a6.y; oG.z += a6.z; oG.w += a6.w;
        oH.x += a7.x; oH.y += a7.y; oH.z += a7.z; oH.w += a7.w;
    }
    for (; c < C; ++c) {
        const float* p = partials + (size_t)(b * C + c) * PSTR;
        L += p[0];
        float4 a = ((const float4*)(p + 8))[tid];
        oA.x += a.x; oA.y += a.y; oA.z += a.z; oA.w += a.w;
    }

    float4 o;
    o.x = ((oA.x + oB.x) + (oC.x + oD.x)) + ((oE.x + oF.x) + (oG.x + oH.x));
    o.y = ((oA.y + oB.y) + (oC.y + oD.y)) + ((oE.y + oF.y) + (oG.y + oH.y));
    o.z = ((oA.z + oB.z) + (oC.z + oD.z)) + ((oE.z + oF.z) + (oG.z + oH.z));
    o.w = ((oA.w + oB.w) + (oC.w + oD.w)) + ((oE.w + oF.w) + (oG.w + oH.w));
    float inv = 1.f / L;
    float4 r; r.x = o.x * inv; r.y = o.y * inv; r.z = o.z * inv; r.w = o.w * inv;
    ((float4*)out)[b * 256 + tid] = r;
}

extern "C" void kernel_launch(void* const* d_in, const int* in_sizes, int n_in,
                              void* d_out, int out_size, void* d_ws, size_t ws_size,
                              hipStream_t stream) {
    const float* x    = (const float*)d_in[0];   // [B,T,D]
    const float* w    = (const float*)d_in[1];   // [D,1]
    const float* bias = (const float*)d_in[2];   // [T,1]
    float* out = (float*)d_out;

    int D = in_sizes[1];            // 1024
    int T = in_sizes[2];            // 2048
    int nrows = in_sizes[0] / D;    // B*T
    int B = nrows / T;              // 32

    int C = T / 64;                 // 64 rows per block -> 16 per wave

    float* partials = (float*)d_ws;

    fused_main<<<dim3(C, B), 256, 0, stream>>>(x, w, bias, partials, T, C);
    combine_kernel<<<B, 256, 0, stream>>>(partials, out, C);
}

// Round 9
// 54.265 us; speedup vs baseline: 1.8763x; 1.8763x over previous
//
#include <hip/hip_runtime.h>

// B=32, T=2048, D=1024 (fp32)
// out[b,d] = sum_t softmax_t(tanh(x[b,t,:]·W + bias[t])) * x[b,t,d]
// tanh in (-1,1) -> exp never overflows -> single pass, no max subtraction.
//
// R9: R8 with the nontemporal-load compile fix (builtin needs a native
// ext_vector_type pointer, not HIP_vector_type). Main = R6's proven body
// (depth-2 register prefetch, 3-slot rotation, no launch_bounds cap).
//  - nontemporal loads on the x stream (use-once data, skip cache fill)
//  - hierarchical 1024-thread combine (4 groups -> LDS -> divide)

#define PSTR 1032  // floats per partial: [0]=lsum, [8..1032)=acc[1024]

typedef float f32x4 __attribute__((ext_vector_type(4)));

__global__ __launch_bounds__(256) void fused_main(
    const float* __restrict__ x, const float* __restrict__ w,
    const float* __restrict__ bias, float* __restrict__ partials,
    int T, int C)
{
    const int c = blockIdx.x;      // T-chunk (64 rows)
    const int b = blockIdx.y;      // batch
    const int wv = threadIdx.x >> 6;
    const int lane = threadIdx.x & 63;
    const int tid = threadIdx.x;

    const int rows_block = T / C;              // 64
    const int rows_wave  = rows_block >> 2;    // 16
    const int r0 = c * rows_block + wv * rows_wave;

    // W fragment: lane l holds w[k*256 + l*4 .. +3]
    const f32x4* w4 = (const f32x4*)w;
    const f32x4 wf0 = w4[lane];
    const f32x4 wf1 = w4[lane + 64];
    const f32x4 wf2 = w4[lane + 128];
    const f32x4 wf3 = w4[lane + 192];

    // bias for this wave's 16 rows, one per lane
    float biasv = (lane < rows_wave) ? bias[r0 + lane] : 0.f;

    const f32x4* xr0 = (const f32x4*)x + ((size_t)b * T + r0) * 256 + lane;

    f32x4 acc0 = {0,0,0,0}, acc1 = {0,0,0,0}, acc2 = {0,0,0,0}, acc3 = {0,0,0,0};
    float lsum = 0.f;

    f32x4 buf[3][4];  // 3-slot rotation; indexed ONLY by constants after unroll

#define LOADG(gg) do {                                        \
    const f32x4* _p = xr0 + (size_t)(gg) * 256;               \
    buf[(gg) % 3][0] = __builtin_nontemporal_load(_p);        \
    buf[(gg) % 3][1] = __builtin_nontemporal_load(_p + 64);   \
    buf[(gg) % 3][2] = __builtin_nontemporal_load(_p + 128);  \
    buf[(gg) % 3][3] = __builtin_nontemporal_load(_p + 192);  \
} while (0)

#define COMPUTEG(gg) do {                                                     \
    f32x4 a0 = buf[(gg) % 3][0], a1 = buf[(gg) % 3][1];                       \
    f32x4 a2 = buf[(gg) % 3][2], a3 = buf[(gg) % 3][3];                       \
    float d = a0.x*wf0.x + a0.y*wf0.y + a0.z*wf0.z + a0.w*wf0.w;              \
    d += a1.x*wf1.x + a1.y*wf1.y + a1.z*wf1.z + a1.w*wf1.w;                   \
    d += a2.x*wf2.x + a2.y*wf2.y + a2.z*wf2.z + a2.w*wf2.w;                   \
    d += a3.x*wf3.x + a3.y*wf3.y + a3.z*wf3.z + a3.w*wf3.w;                   \
    _Pragma("unroll")                                                         \
    for (int off = 1; off < 64; off <<= 1) d += __shfl_xor(d, off);           \
    float _a = d + __shfl(biasv, (gg));                                       \
    float _t = 1.f - 2.f / (__expf(2.f * _a) + 1.f);   /* tanh, inf-safe */   \
    float e = __expf(_t);                                                     \
    lsum += e;                                                                \
    acc0 += e * a0; acc1 += e * a1; acc2 += e * a2; acc3 += e * a3;           \
} while (0)

    LOADG(0);
    LOADG(1);
#pragma unroll
    for (int g = 0; g < 16; ++g) {   // rows_wave == 16 (host guarantees)
        if (g < 14) LOADG(g + 2);    // two rows always in flight during compute
        COMPUTEG(g);
    }

#undef LOADG
#undef COMPUTEG

    // combine 4 waves via LDS -> one partial per block
    __shared__ f32x4 lacc4[4 * 256];
    __shared__ float lls[4];
    lacc4[wv * 256 + lane]       = acc0;
    lacc4[wv * 256 + 64 + lane]  = acc1;
    lacc4[wv * 256 + 128 + lane] = acc2;
    lacc4[wv * 256 + 192 + lane] = acc3;
    if (lane == 0) lls[wv] = lsum;
    __syncthreads();

    f32x4 o0 = lacc4[tid];
    f32x4 o1 = lacc4[256 + tid];
    f32x4 o2 = lacc4[512 + tid];
    f32x4 o3 = lacc4[768 + tid];
    f32x4 o = (o0 + o1) + (o2 + o3);

    float* p = partials + (size_t)(b * C + c) * PSTR;
    if (tid == 0) p[0] = (lls[0] + lls[1]) + (lls[2] + lls[3]);
    ((f32x4*)(p + 8))[tid] = o;
}

// 1024 threads: 4 groups of 256; group g sums chunks [g*C/4, (g+1)*C/4).
// Requires C % 4 == 0 (host guarantees: C = T/64 = 32).
__global__ __launch_bounds__(1024) void combine_kernel(
    const float* __restrict__ partials, float* __restrict__ out, int C)
{
    const int b = blockIdx.x;
    const int tid = threadIdx.x & 255;
    const int grp = threadIdx.x >> 8;
    const int cq = C >> 2;
    const int c0 = grp * cq;

    float L0 = 0.f, L1 = 0.f, L2 = 0.f, L3 = 0.f;
    f32x4 o0 = {0,0,0,0}, o1 = {0,0,0,0}, o2 = {0,0,0,0}, o3 = {0,0,0,0};

    int c = 0;
    for (; c + 4 <= cq; c += 4) {
        const float* p0 = partials + (size_t)(b * C + c0 + c) * PSTR;
        const float* p1 = p0 + PSTR;
        const float* p2 = p1 + PSTR;
        const float* p3 = p2 + PSTR;
        float l0 = p0[0], l1 = p1[0], l2 = p2[0], l3 = p3[0];
        f32x4 a0 = ((const f32x4*)(p0 + 8))[tid];
        f32x4 a1 = ((const f32x4*)(p1 + 8))[tid];
        f32x4 a2 = ((const f32x4*)(p2 + 8))[tid];
        f32x4 a3 = ((const f32x4*)(p3 + 8))[tid];
        L0 += l0; L1 += l1; L2 += l2; L3 += l3;
        o0 += a0; o1 += a1; o2 += a2; o3 += a3;
    }
    for (; c < cq; ++c) {
        const float* p = partials + (size_t)(b * C + c0 + c) * PSTR;
        L0 += p[0];
        o0 += ((const f32x4*)(p + 8))[tid];
    }

    float L = (L0 + L1) + (L2 + L3);
    f32x4 o = (o0 + o1) + (o2 + o3);

    __shared__ f32x4 red[4][256];
    __shared__ float redl[4];
    red[grp][tid] = o;
    if (tid == 0) redl[grp] = L;
    __syncthreads();

    if (grp == 0) {
        f32x4 s = (red[0][tid] + red[1][tid]) + (red[2][tid] + red[3][tid]);
        float Lt = (redl[0] + redl[1]) + (redl[2] + redl[3]);
        float inv = 1.f / Lt;
        f32x4 r = s * inv;
        ((f32x4*)out)[b * 256 + tid] = r;
    }
}

extern "C" void kernel_launch(void* const* d_in, const int* in_sizes, int n_in,
                              void* d_out, int out_size, void* d_ws, size_t ws_size,
                              hipStream_t stream) {
    const float* x    = (const float*)d_in[0];   // [B,T,D]
    const float* w    = (const float*)d_in[1];   // [D,1]
    const float* bias = (const float*)d_in[2];   // [T,1]
    float* out = (float*)d_out;

    int D = in_sizes[1];            // 1024
    int T = in_sizes[2];            // 2048
    int nrows = in_sizes[0] / D;    // B*T
    int B = nrows / T;              // 32

    int C = T / 64;                 // 64 rows per block -> 16 per wave; C=32

    float* partials = (float*)d_ws;

    fused_main<<<dim3(C, B), 256, 0, stream>>>(x, w, bias, partials, T, C);
    combine_kernel<<<B, 1024, 0, stream>>>(partials, out, C);
}

// Round 10
// 52.936 us; speedup vs baseline: 1.9234x; 1.0251x over previous
//
#include <hip/hip_runtime.h>

// B=32, T=2048, D=1024 (fp32)
// out[b,d] = sum_t softmax_t(tanh(x[b,t,:]·W + bias[t])) * x[b,t,d]
// tanh in (-1,1) -> exp never overflows -> single pass, no max subtraction.
//
// R10: R6's proven body with depth-3 register prefetch (4-slot rotation),
// WITHOUT __launch_bounds__ min-wave cap (R7 post-mortem: (256,4) forced
// VGPR<=128 -> scratch spill. Uncapped, est. ~125 VGPR fits 4 waves/SIMD).
// Plain loads (R9 post-mortem: nontemporal hint was ~1us worse). Hierarchical
// 1024-thread combine kept from R9.

#define PSTR 1032  // floats per partial: [0]=lsum, [8..1032)=acc[1024]

typedef float f32x4 __attribute__((ext_vector_type(4)));

__global__ __launch_bounds__(256) void fused_main(
    const float* __restrict__ x, const float* __restrict__ w,
    const float* __restrict__ bias, float* __restrict__ partials,
    int T, int C)
{
    const int c = blockIdx.x;      // T-chunk (64 rows)
    const int b = blockIdx.y;      // batch
    const int wv = threadIdx.x >> 6;
    const int lane = threadIdx.x & 63;
    const int tid = threadIdx.x;

    const int rows_block = T / C;              // 64
    const int rows_wave  = rows_block >> 2;    // 16
    const int r0 = c * rows_block + wv * rows_wave;

    // W fragment: lane l holds w[k*256 + l*4 .. +3]
    const f32x4* w4 = (const f32x4*)w;
    const f32x4 wf0 = w4[lane];
    const f32x4 wf1 = w4[lane + 64];
    const f32x4 wf2 = w4[lane + 128];
    const f32x4 wf3 = w4[lane + 192];

    // bias for this wave's 16 rows, one per lane
    float biasv = (lane < rows_wave) ? bias[r0 + lane] : 0.f;

    const f32x4* xr0 = (const f32x4*)x + ((size_t)b * T + r0) * 256 + lane;

    f32x4 acc0 = {0,0,0,0}, acc1 = {0,0,0,0}, acc2 = {0,0,0,0}, acc3 = {0,0,0,0};
    float lsum = 0.f;

    f32x4 buf[4][4];  // 4-slot rotation; indexed ONLY by constants after unroll

#define LOADG(gg) do {                                   \
    const f32x4* _p = xr0 + (size_t)(gg) * 256;          \
    buf[(gg) & 3][0] = _p[0];                            \
    buf[(gg) & 3][1] = _p[64];                           \
    buf[(gg) & 3][2] = _p[128];                          \
    buf[(gg) & 3][3] = _p[192];                          \
} while (0)

#define COMPUTEG(gg) do {                                                     \
    f32x4 a0 = buf[(gg) & 3][0], a1 = buf[(gg) & 3][1];                       \
    f32x4 a2 = buf[(gg) & 3][2], a3 = buf[(gg) & 3][3];                       \
    float d = a0.x*wf0.x + a0.y*wf0.y + a0.z*wf0.z + a0.w*wf0.w;              \
    d += a1.x*wf1.x + a1.y*wf1.y + a1.z*wf1.z + a1.w*wf1.w;                   \
    d += a2.x*wf2.x + a2.y*wf2.y + a2.z*wf2.z + a2.w*wf2.w;                   \
    d += a3.x*wf3.x + a3.y*wf3.y + a3.z*wf3.z + a3.w*wf3.w;                   \
    _Pragma("unroll")                                                         \
    for (int off = 1; off < 64; off <<= 1) d += __shfl_xor(d, off);           \
    float _a = d + __shfl(biasv, (gg));                                       \
    float _t = 1.f - 2.f / (__expf(2.f * _a) + 1.f);   /* tanh, inf-safe */   \
    float e = __expf(_t);                                                     \
    lsum += e;                                                                \
    acc0 += e * a0; acc1 += e * a1; acc2 += e * a2; acc3 += e * a3;           \
} while (0)

    LOADG(0);
    LOADG(1);
    LOADG(2);
#pragma unroll
    for (int g = 0; g < 16; ++g) {   // rows_wave == 16 (host guarantees)
        if (g < 13) LOADG(g + 3);    // three rows always in flight during compute
        COMPUTEG(g);
    }

#undef LOADG
#undef COMPUTEG

    // combine 4 waves via LDS -> one partial per block
    __shared__ f32x4 lacc4[4 * 256];
    __shared__ float lls[4];
    lacc4[wv * 256 + lane]       = acc0;
    lacc4[wv * 256 + 64 + lane]  = acc1;
    lacc4[wv * 256 + 128 + lane] = acc2;
    lacc4[wv * 256 + 192 + lane] = acc3;
    if (lane == 0) lls[wv] = lsum;
    __syncthreads();

    f32x4 o0 = lacc4[tid];
    f32x4 o1 = lacc4[256 + tid];
    f32x4 o2 = lacc4[512 + tid];
    f32x4 o3 = lacc4[768 + tid];
    f32x4 o = (o0 + o1) + (o2 + o3);

    float* p = partials + (size_t)(b * C + c) * PSTR;
    if (tid == 0) p[0] = (lls[0] + lls[1]) + (lls[2] + lls[3]);
    ((f32x4*)(p + 8))[tid] = o;
}

// 1024 threads: 4 groups of 256; group g sums chunks [g*C/4, (g+1)*C/4).
// Requires C % 4 == 0 (host guarantees: C = T/64 = 32).
__global__ __launch_bounds__(1024) void combine_kernel(
    const float* __restrict__ partials, float* __restrict__ out, int C)
{
    const int b = blockIdx.x;
    const int tid = threadIdx.x & 255;
    const int grp = threadIdx.x >> 8;
    const int cq = C >> 2;
    const int c0 = grp * cq;

    float L0 = 0.f, L1 = 0.f, L2 = 0.f, L3 = 0.f;
    f32x4 o0 = {0,0,0,0}, o1 = {0,0,0,0}, o2 = {0,0,0,0}, o3 = {0,0,0,0};

    int c = 0;
    for (; c + 4 <= cq; c += 4) {
        const float* p0 = partials + (size_t)(b * C + c0 + c) * PSTR;
        const float* p1 = p0 + PSTR;
        const float* p2 = p1 + PSTR;
        const float* p3 = p2 + PSTR;
        float l0 = p0[0], l1 = p1[0], l2 = p2[0], l3 = p3[0];
        f32x4 a0 = ((const f32x4*)(p0 + 8))[tid];
        f32x4 a1 = ((const f32x4*)(p1 + 8))[tid];
        f32x4 a2 = ((const f32x4*)(p2 + 8))[tid];
        f32x4 a3 = ((const f32x4*)(p3 + 8))[tid];
        L0 += l0; L1 += l1; L2 += l2; L3 += l3;
        o0 += a0; o1 += a1; o2 += a2; o3 += a3;
    }
    for (; c < cq; ++c) {
        const float* p = partials + (size_t)(b * C + c0 + c) * PSTR;
        L0 += p[0];
        o0 += ((const f32x4*)(p + 8))[tid];
    }

    float L = (L0 + L1) + (L2 + L3);
    f32x4 o = (o0 + o1) + (o2 + o3);

    __shared__ f32x4 red[4][256];
    __shared__ float redl[4];
    red[grp][tid] = o;
    if (tid == 0) redl[grp] = L;
    __syncthreads();

    if (grp == 0) {
        f32x4 s = (red[0][tid] + red[1][tid]) + (red[2][tid] + red[3][tid]);
        float Lt = (redl[0] + redl[1]) + (redl[2] + redl[3]);
        float inv = 1.f / Lt;
        f32x4 r = s * inv;
        ((f32x4*)out)[b * 256 + tid] = r;
    }
}

extern "C" void kernel_launch(void* const* d_in, const int* in_sizes, int n_in,
                              void* d_out, int out_size, void* d_ws, size_t ws_size,
                              hipStream_t stream) {
    const float* x    = (const float*)d_in[0];   // [B,T,D]
    const float* w    = (const float*)d_in[1];   // [D,1]
    const float* bias = (const float*)d_in[2];   // [T,1]
    float* out = (float*)d_out;

    int D = in_sizes[1];            // 1024
    int T = in_sizes[2];            // 2048
    int nrows = in_sizes[0] / D;    // B*T
    int B = nrows / T;              // 32

    int C = T / 64;                 // 64 rows per block -> 16 per wave; C=32

    float* partials = (float*)d_ws;

    fused_main<<<dim3(C, B), 256, 0, stream>>>(x, w, bias, partials, T, C);
    combine_kernel<<<B, 1024, 0, stream>>>(partials, out, C);
}

// Round 11
// 52.546 us; speedup vs baseline: 1.9377x; 1.0074x over previous
//
#include <hip/hip_runtime.h>

// B=32, T=2048, D=1024 (fp32)
// out[b,d] = sum_t softmax_t(tanh(x[b,t,:]·W + bias[t])) * x[b,t,d]
// tanh in (-1,1) -> exp never overflows -> single pass, no max subtraction.
//
// R11: main = R10 body (depth-3 register prefetch, 4-slot rotation, no
// launch_bounds cap) with the dot split into 4 independent partials.
// Combine parallelized: grid (4,B), each block does a 256-float d-slice,
// 8 independent loads in flight per wave, redundant per-wave L reduction.

#define PSTR 1032  // floats per partial: [0]=lsum, [8..1032)=acc[1024]

typedef float f32x4 __attribute__((ext_vector_type(4)));

__global__ __launch_bounds__(256) void fused_main(
    const float* __restrict__ x, const float* __restrict__ w,
    const float* __restrict__ bias, float* __restrict__ partials,
    int T, int C)
{
    const int c = blockIdx.x;      // T-chunk (64 rows)
    const int b = blockIdx.y;      // batch
    const int wv = threadIdx.x >> 6;
    const int lane = threadIdx.x & 63;
    const int tid = threadIdx.x;

    const int rows_block = T / C;              // 64
    const int rows_wave  = rows_block >> 2;    // 16
    const int r0 = c * rows_block + wv * rows_wave;

    // W fragment: lane l holds w[k*256 + l*4 .. +3]
    const f32x4* w4 = (const f32x4*)w;
    const f32x4 wf0 = w4[lane];
    const f32x4 wf1 = w4[lane + 64];
    const f32x4 wf2 = w4[lane + 128];
    const f32x4 wf3 = w4[lane + 192];

    // bias for this wave's 16 rows, one per lane
    float biasv = (lane < rows_wave) ? bias[r0 + lane] : 0.f;

    const f32x4* xr0 = (const f32x4*)x + ((size_t)b * T + r0) * 256 + lane;

    f32x4 acc0 = {0,0,0,0}, acc1 = {0,0,0,0}, acc2 = {0,0,0,0}, acc3 = {0,0,0,0};
    float lsum = 0.f;

    f32x4 buf[4][4];  // 4-slot rotation; indexed ONLY by constants after unroll

#define LOADG(gg) do {                                   \
    const f32x4* _p = xr0 + (size_t)(gg) * 256;          \
    buf[(gg) & 3][0] = _p[0];                            \
    buf[(gg) & 3][1] = _p[64];                           \
    buf[(gg) & 3][2] = _p[128];                          \
    buf[(gg) & 3][3] = _p[192];                          \
} while (0)

#define COMPUTEG(gg) do {                                                     \
    f32x4 a0 = buf[(gg) & 3][0], a1 = buf[(gg) & 3][1];                       \
    f32x4 a2 = buf[(gg) & 3][2], a3 = buf[(gg) & 3][3];                       \
    float d0 = a0.x*wf0.x + a0.y*wf0.y + a0.z*wf0.z + a0.w*wf0.w;             \
    float d1 = a1.x*wf1.x + a1.y*wf1.y + a1.z*wf1.z + a1.w*wf1.w;             \
    float d2 = a2.x*wf2.x + a2.y*wf2.y + a2.z*wf2.z + a2.w*wf2.w;             \
    float d3 = a3.x*wf3.x + a3.y*wf3.y + a3.z*wf3.z + a3.w*wf3.w;             \
    float d = (d0 + d1) + (d2 + d3);                                          \
    _Pragma("unroll")                                                         \
    for (int off = 1; off < 64; off <<= 1) d += __shfl_xor(d, off);           \
    float _a = d + __shfl(biasv, (gg));                                       \
    float _t = 1.f - 2.f / (__expf(2.f * _a) + 1.f);   /* tanh, inf-safe */   \
    float e = __expf(_t);                                                     \
    lsum += e;                                                                \
    acc0 += e * a0; acc1 += e * a1; acc2 += e * a2; acc3 += e * a3;           \
} while (0)

    LOADG(0);
    LOADG(1);
    LOADG(2);
#pragma unroll
    for (int g = 0; g < 16; ++g) {   // rows_wave == 16 (host guarantees)
        if (g < 13) LOADG(g + 3);    // three rows always in flight during compute
        COMPUTEG(g);
    }

#undef LOADG
#undef COMPUTEG

    // combine 4 waves via LDS -> one partial per block
    __shared__ f32x4 lacc4[4 * 256];
    __shared__ float lls[4];
    lacc4[wv * 256 + lane]       = acc0;
    lacc4[wv * 256 + 64 + lane]  = acc1;
    lacc4[wv * 256 + 128 + lane] = acc2;
    lacc4[wv * 256 + 192 + lane] = acc3;
    if (lane == 0) lls[wv] = lsum;
    __syncthreads();

    f32x4 o0 = lacc4[tid];
    f32x4 o1 = lacc4[256 + tid];
    f32x4 o2 = lacc4[512 + tid];
    f32x4 o3 = lacc4[768 + tid];
    f32x4 o = (o0 + o1) + (o2 + o3);

    float* p = partials + (size_t)(b * C + c) * PSTR;
    if (tid == 0) p[0] = (lls[0] + lls[1]) + (lls[2] + lls[3]);
    ((f32x4*)(p + 8))[tid] = o;
}

// Parallel combine for C==32: grid (4, B), 256 threads.
// Block (s,b): d-slice s (256 floats = 64 f32x4). Wave w sums chunks
// w*8..w*8+7 (8 independent loads in flight). Every wave redundantly
// reduces the 32 lsums (tiny, L2-hit) -> no extra sync for L.
__global__ __launch_bounds__(256) void combine32_kernel(
    const float* __restrict__ partials, float* __restrict__ out)
{
    const int s = blockIdx.x;          // d-slice
    const int b = blockIdx.y;          // batch
    const int wv = threadIdx.x >> 6;
    const int lane = threadIdx.x & 63;

    const float* pb = partials + (size_t)b * 32 * PSTR;

    // L: lanes load lsum[lane&31] (both halves identical), butterfly 5 stages
    float L = pb[(size_t)(lane & 31) * PSTR];
#pragma unroll
    for (int off = 1; off < 32; off <<= 1) L += __shfl_xor(L, off);

    // sum 8 chunks for this wave, independent chains
    const int c0 = wv * 8;
    const int idx = s * 64 + lane;     // f32x4 index within acc[1024]
    f32x4 a0 = ((const f32x4*)(pb + (size_t)(c0 + 0) * PSTR + 8))[idx];
    f32x4 a1 = ((const f32x4*)(pb + (size_t)(c0 + 1) * PSTR + 8))[idx];
    f32x4 a2 = ((const f32x4*)(pb + (size_t)(c0 + 2) * PSTR + 8))[idx];
    f32x4 a3 = ((const f32x4*)(pb + (size_t)(c0 + 3) * PSTR + 8))[idx];
    f32x4 a4 = ((const f32x4*)(pb + (size_t)(c0 + 4) * PSTR + 8))[idx];
    f32x4 a5 = ((const f32x4*)(pb + (size_t)(c0 + 5) * PSTR + 8))[idx];
    f32x4 a6 = ((const f32x4*)(pb + (size_t)(c0 + 6) * PSTR + 8))[idx];
    f32x4 a7 = ((const f32x4*)(pb + (size_t)(c0 + 7) * PSTR + 8))[idx];
    f32x4 o = ((a0 + a1) + (a2 + a3)) + ((a4 + a5) + (a6 + a7));

    __shared__ f32x4 red[4][64];
    red[wv][lane] = o;
    __syncthreads();

    if (wv == 0) {
        f32x4 t = (red[0][lane] + red[1][lane]) + (red[2][lane] + red[3][lane]);
        f32x4 r = t * (1.f / L);
        ((f32x4*)out)[b * 256 + s * 64 + lane] = r;
    }
}

// Fallback for C != 32 (not hit with T=2048): serial per-batch combine.
__global__ __launch_bounds__(256) void combine_generic(
    const float* __restrict__ partials, float* __restrict__ out, int C)
{
    const int b = blockIdx.x;
    const int tid = threadIdx.x;
    float L = 0.f;
    f32x4 o = {0.f, 0.f, 0.f, 0.f};
    for (int c = 0; c < C; ++c) {
        const float* p = partials + (size_t)(b * C + c) * PSTR;
        L += p[0];
        o += ((const f32x4*)(p + 8))[tid];
    }
    f32x4 r = o * (1.f / L);
    ((f32x4*)out)[b * 256 + tid] = r;
}

extern "C" void kernel_launch(void* const* d_in, const int* in_sizes, int n_in,
                              void* d_out, int out_size, void* d_ws, size_t ws_size,
                              hipStream_t stream) {
    const float* x    = (const float*)d_in[0];   // [B,T,D]
    const float* w    = (const float*)d_in[1];   // [D,1]
    const float* bias = (const float*)d_in[2];   // [T,1]
    float* out = (float*)d_out;

    int D = in_sizes[1];            // 1024
    int T = in_sizes[2];            // 2048
    int nrows = in_sizes[0] / D;    // B*T
    int B = nrows / T;              // 32

    int C = T / 64;                 // 64 rows per block -> 16 per wave; C=32

    float* partials = (float*)d_ws;

    fused_main<<<dim3(C, B), 256, 0, stream>>>(x, w, bias, partials, T, C);
    if (C == 32)
        combine32_kernel<<<dim3(4, B), 256, 0, stream>>>(partials, out);
    else
        combine_generic<<<B, 256, 0, stream>>>(partials, out, C);
}

// Round 12
// 47.858 us; speedup vs baseline: 2.1275x; 1.0980x over previous
//
#include <hip/hip_runtime.h>

// B=32, T=2048, D=1024 (fp32)
// out[b,d] = sum_t softmax_t(tanh(x[b,t,:]·W + bias[t])) * x[b,t,d]
// tanh in (-1,1) -> exp never overflows -> single pass, no max subtraction.
//
// R12: identical to R11 except the row->wave map inside a block is
// INTERLEAVED (wave w handles rows w, w+4, w+8, ... of the block's 64)
// so each block is one sequential 256KB stream (DRAM row-buffer locality)
// instead of 4 streams 64KB apart.

#define PSTR 1032  // floats per partial: [0]=lsum, [8..1032)=acc[1024]

typedef float f32x4 __attribute__((ext_vector_type(4)));

__global__ __launch_bounds__(256) void fused_main(
    const float* __restrict__ x, const float* __restrict__ w,
    const float* __restrict__ bias, float* __restrict__ partials,
    int T, int C)
{
    const int c = blockIdx.x;      // T-chunk (64 rows)
    const int b = blockIdx.y;      // batch
    const int wv = threadIdx.x >> 6;
    const int lane = threadIdx.x & 63;
    const int tid = threadIdx.x;

    const int rows_block = T / C;              // 64
    const int r0 = c * rows_block;             // block's first row
    // wave wv handles rows r0 + wv + 4*g, g = 0..15 (interleaved)

    // W fragment: lane l holds w[k*256 + l*4 .. +3]
    const f32x4* w4 = (const f32x4*)w;
    const f32x4 wf0 = w4[lane];
    const f32x4 wf1 = w4[lane + 64];
    const f32x4 wf2 = w4[lane + 128];
    const f32x4 wf3 = w4[lane + 192];

    // bias for this wave's 16 rows, one per lane: row = r0 + wv + 4*lane
    float biasv = (lane < 16) ? bias[r0 + wv + 4 * lane] : 0.f;

    // wave's row g is at (b*T + r0 + wv + 4*g) * 256 f32x4
    const f32x4* xr0 = (const f32x4*)x + ((size_t)b * T + r0 + wv) * 256 + lane;

    f32x4 acc0 = {0,0,0,0}, acc1 = {0,0,0,0}, acc2 = {0,0,0,0}, acc3 = {0,0,0,0};
    float lsum = 0.f;

    f32x4 buf[4][4];  // 4-slot rotation; indexed ONLY by constants after unroll

#define LOADG(gg) do {                                   \
    const f32x4* _p = xr0 + (size_t)(gg) * 1024;         \
    buf[(gg) & 3][0] = _p[0];                            \
    buf[(gg) & 3][1] = _p[64];                           \
    buf[(gg) & 3][2] = _p[128];                          \
    buf[(gg) & 3][3] = _p[192];                          \
} while (0)

#define COMPUTEG(gg) do {                                                     \
    f32x4 a0 = buf[(gg) & 3][0], a1 = buf[(gg) & 3][1];                       \
    f32x4 a2 = buf[(gg) & 3][2], a3 = buf[(gg) & 3][3];                       \
    float d0 = a0.x*wf0.x + a0.y*wf0.y + a0.z*wf0.z + a0.w*wf0.w;             \
    float d1 = a1.x*wf1.x + a1.y*wf1.y + a1.z*wf1.z + a1.w*wf1.w;             \
    float d2 = a2.x*wf2.x + a2.y*wf2.y + a2.z*wf2.z + a2.w*wf2.w;             \
    float d3 = a3.x*wf3.x + a3.y*wf3.y + a3.z*wf3.z + a3.w*wf3.w;             \
    float d = (d0 + d1) + (d2 + d3);                                          \
    _Pragma("unroll")                                                         \
    for (int off = 1; off < 64; off <<= 1) d += __shfl_xor(d, off);           \
    float _a = d + __shfl(biasv, (gg));                                       \
    float _t = 1.f - 2.f / (__expf(2.f * _a) + 1.f);   /* tanh, inf-safe */   \
    float e = __expf(_t);                                                     \
    lsum += e;                                                                \
    acc0 += e * a0; acc1 += e * a1; acc2 += e * a2; acc3 += e * a3;           \
} while (0)

    LOADG(0);
    LOADG(1);
    LOADG(2);
#pragma unroll
    for (int g = 0; g < 16; ++g) {   // 16 rows per wave (host guarantees)
        if (g < 13) LOADG(g + 3);    // three rows always in flight during compute
        COMPUTEG(g);
    }

#undef LOADG
#undef COMPUTEG

    // combine 4 waves via LDS -> one partial per block
    __shared__ f32x4 lacc4[4 * 256];
    __shared__ float lls[4];
    lacc4[wv * 256 + lane]       = acc0;
    lacc4[wv * 256 + 64 + lane]  = acc1;
    lacc4[wv * 256 + 128 + lane] = acc2;
    lacc4[wv * 256 + 192 + lane] = acc3;
    if (lane == 0) lls[wv] = lsum;
    __syncthreads();

    f32x4 o0 = lacc4[tid];
    f32x4 o1 = lacc4[256 + tid];
    f32x4 o2 = lacc4[512 + tid];
    f32x4 o3 = lacc4[768 + tid];
    f32x4 o = (o0 + o1) + (o2 + o3);

    float* p = partials + (size_t)(b * C + c) * PSTR;
    if (tid == 0) p[0] = (lls[0] + lls[1]) + (lls[2] + lls[3]);
    ((f32x4*)(p + 8))[tid] = o;
}

// Parallel combine for C==32: grid (4, B), 256 threads.
__global__ __launch_bounds__(256) void combine32_kernel(
    const float* __restrict__ partials, float* __restrict__ out)
{
    const int s = blockIdx.x;          // d-slice
    const int b = blockIdx.y;          // batch
    const int wv = threadIdx.x >> 6;
    const int lane = threadIdx.x & 63;

    const float* pb = partials + (size_t)b * 32 * PSTR;

    // L: lanes load lsum[lane&31] (both halves identical), butterfly 5 stages
    float L = pb[(size_t)(lane & 31) * PSTR];
#pragma unroll
    for (int off = 1; off < 32; off <<= 1) L += __shfl_xor(L, off);

    // sum 8 chunks for this wave, independent chains
    const int c0 = wv * 8;
    const int idx = s * 64 + lane;     // f32x4 index within acc[1024]
    f32x4 a0 = ((const f32x4*)(pb + (size_t)(c0 + 0) * PSTR + 8))[idx];
    f32x4 a1 = ((const f32x4*)(pb + (size_t)(c0 + 1) * PSTR + 8))[idx];
    f32x4 a2 = ((const f32x4*)(pb + (size_t)(c0 + 2) * PSTR + 8))[idx];
    f32x4 a3 = ((const f32x4*)(pb + (size_t)(c0 + 3) * PSTR + 8))[idx];
    f32x4 a4 = ((const f32x4*)(pb + (size_t)(c0 + 4) * PSTR + 8))[idx];
    f32x4 a5 = ((const f32x4*)(pb + (size_t)(c0 + 5) * PSTR + 8))[idx];
    f32x4 a6 = ((const f32x4*)(pb + (size_t)(c0 + 6) * PSTR + 8))[idx];
    f32x4 a7 = ((const f32x4*)(pb + (size_t)(c0 + 7) * PSTR + 8))[idx];
    f32x4 o = ((a0 + a1) + (a2 + a3)) + ((a4 + a5) + (a6 + a7));

    __shared__ f32x4 red[4][64];
    red[wv][lane] = o;
    __syncthreads();

    if (wv == 0) {
        f32x4 t = (red[0][lane] + red[1][lane]) + (red[2][lane] + red[3][lane]);
        f32x4 r = t * (1.f / L);
        ((f32x4*)out)[b * 256 + s * 64 + lane] = r;
    }
}

// Fallback for C != 32 (not hit with T=2048): serial per-batch combine.
__global__ __launch_bounds__(256) void combine_generic(
    const float* __restrict__ partials, float* __restrict__ out, int C)
{
    const int b = blockIdx.x;
    const int tid = threadIdx.x;
    float L = 0.f;
    f32x4 o = {0.f, 0.f, 0.f, 0.f};
    for (int c = 0; c < C; ++c) {
        const float* p = partials + (size_t)(b * C + c) * PSTR;
        L += p[0];
        o += ((const f32x4*)(p + 8))[tid];
    }
    f32x4 r = o * (1.f / L);
    ((f32x4*)out)[b * 256 + tid] = r;
}

extern "C" void kernel_launch(void* const* d_in, const int* in_sizes, int n_in,
                              void* d_out, int out_size, void* d_ws, size_t ws_size,
                              hipStream_t stream) {
    const float* x    = (const float*)d_in[0];   // [B,T,D]
    const float* w    = (const float*)d_in[1];   // [D,1]
    const float* bias = (const float*)d_in[2];   // [T,1]
    float* out = (float*)d_out;

    int D = in_sizes[1];            // 1024
    int T = in_sizes[2];            // 2048
    int nrows = in_sizes[0] / D;    // B*T
    int B = nrows / T;              // 32

    int C = T / 64;                 // 64 rows per block -> 16 per wave; C=32

    float* partials = (float*)d_ws;

    fused_main<<<dim3(C, B), 256, 0, stream>>>(x, w, bias, partials, T, C);
    if (C == 32)
        combine32_kernel<<<dim3(4, B), 256, 0, stream>>>(partials, out);
    else
        combine_generic<<<B, 256, 0, stream>>>(partials, out, C);
}

// Round 13
// 47.781 us; speedup vs baseline: 2.1309x; 1.0016x over previous
//
#include <hip/hip_runtime.h>

// B=32, T=2048, D=1024 (fp32)
// out[b,d] = sum_t softmax_t(tanh(x[b,t,:]·W + bias[t])) * x[b,t,d]
// tanh in (-1,1) -> exp never overflows -> single pass, no max subtraction.
//
// R13: R12's interleaved-stream structure scaled to 512-thread blocks:
// 8 waves, wave w handles rows w+8g -> each block is ONE sequential 512KB
// stream; concurrent streams 1024 -> 512 (DRAM row-buffer locality).
// Occupancy unchanged (2 blocks/CU x 8 waves = 16 waves/CU).

#define PSTR 1032  // floats per partial: [0]=lsum, [8..1032)=acc[1024]

typedef float f32x4 __attribute__((ext_vector_type(4)));

__global__ __launch_bounds__(512) void fused_main(
    const float* __restrict__ x, const float* __restrict__ w,
    const float* __restrict__ bias, float* __restrict__ partials,
    int T, int C)
{
    const int c = blockIdx.x;      // T-chunk (128 rows)
    const int b = blockIdx.y;      // batch
    const int wv = threadIdx.x >> 6;   // 0..7
    const int lane = threadIdx.x & 63;
    const int tid = threadIdx.x;

    const int rows_block = T / C;              // 128
    const int r0 = c * rows_block;             // block's first row
    // wave wv handles rows r0 + wv + 8*g, g = 0..15 (interleaved)

    // W fragment: lane l holds w[k*256 + l*4 .. +3]
    const f32x4* w4 = (const f32x4*)w;
    const f32x4 wf0 = w4[lane];
    const f32x4 wf1 = w4[lane + 64];
    const f32x4 wf2 = w4[lane + 128];
    const f32x4 wf3 = w4[lane + 192];

    // bias for this wave's 16 rows, one per lane: row = r0 + wv + 8*lane
    float biasv = (lane < 16) ? bias[r0 + wv + 8 * lane] : 0.f;

    // wave's row g is at (b*T + r0 + wv + 8*g) * 256 f32x4
    const f32x4* xr0 = (const f32x4*)x + ((size_t)b * T + r0 + wv) * 256 + lane;

    f32x4 acc0 = {0,0,0,0}, acc1 = {0,0,0,0}, acc2 = {0,0,0,0}, acc3 = {0,0,0,0};
    float lsum = 0.f;

    f32x4 buf[4][4];  // 4-slot rotation; indexed ONLY by constants after unroll

#define LOADG(gg) do {                                   \
    const f32x4* _p = xr0 + (size_t)(gg) * 2048;         \
    buf[(gg) & 3][0] = _p[0];                            \
    buf[(gg) & 3][1] = _p[64];                           \
    buf[(gg) & 3][2] = _p[128];                          \
    buf[(gg) & 3][3] = _p[192];                          \
} while (0)

#define COMPUTEG(gg) do {                                                     \
    f32x4 a0 = buf[(gg) & 3][0], a1 = buf[(gg) & 3][1];                       \
    f32x4 a2 = buf[(gg) & 3][2], a3 = buf[(gg) & 3][3];                       \
    float d0 = a0.x*wf0.x + a0.y*wf0.y + a0.z*wf0.z + a0.w*wf0.w;             \
    float d1 = a1.x*wf1.x + a1.y*wf1.y + a1.z*wf1.z + a1.w*wf1.w;             \
    float d2 = a2.x*wf2.x + a2.y*wf2.y + a2.z*wf2.z + a2.w*wf2.w;             \
    float d3 = a3.x*wf3.x + a3.y*wf3.y + a3.z*wf3.z + a3.w*wf3.w;             \
    float d = (d0 + d1) + (d2 + d3);                                          \
    _Pragma("unroll")                                                         \
    for (int off = 1; off < 64; off <<= 1) d += __shfl_xor(d, off);           \
    float _a = d + __shfl(biasv, (gg));                                       \
    float _t = 1.f - 2.f / (__expf(2.f * _a) + 1.f);   /* tanh, inf-safe */   \
    float e = __expf(_t);                                                     \
    lsum += e;                                                                \
    acc0 += e * a0; acc1 += e * a1; acc2 += e * a2; acc3 += e * a3;           \
} while (0)

    LOADG(0);
    LOADG(1);
    LOADG(2);
#pragma unroll
    for (int g = 0; g < 16; ++g) {   // 16 rows per wave (host guarantees)
        if (g < 13) LOADG(g + 3);    // three rows always in flight during compute
        COMPUTEG(g);
    }

#undef LOADG
#undef COMPUTEG

    // combine 8 waves via LDS -> one partial per block
    __shared__ f32x4 lacc4[8 * 256];
    __shared__ float lls[8];
    lacc4[wv * 256 + lane]       = acc0;
    lacc4[wv * 256 + 64 + lane]  = acc1;
    lacc4[wv * 256 + 128 + lane] = acc2;
    lacc4[wv * 256 + 192 + lane] = acc3;
    if (lane == 0) lls[wv] = lsum;
    __syncthreads();

    if (tid < 256) {
        f32x4 o = ((lacc4[tid]        + lacc4[256 + tid])
                 + (lacc4[512 + tid]  + lacc4[768 + tid]))
                + ((lacc4[1024 + tid] + lacc4[1280 + tid])
                 + (lacc4[1536 + tid] + lacc4[1792 + tid]));

        float* p = partials + (size_t)(b * C + c) * PSTR;
        if (tid == 0)
            p[0] = ((lls[0] + lls[1]) + (lls[2] + lls[3]))
                 + ((lls[4] + lls[5]) + (lls[6] + lls[7]));
        ((f32x4*)(p + 8))[tid] = o;
    }
}

// Parallel combine for C==16: grid (4, B), 256 threads.
// Block (s,b): d-slice s (256 floats = 64 f32x4). Wave wv sums chunks
// wv*4..wv*4+3. Every wave redundantly reduces the 16 lsums.
__global__ __launch_bounds__(256) void combine16_kernel(
    const float* __restrict__ partials, float* __restrict__ out)
{
    const int s = blockIdx.x;          // d-slice
    const int b = blockIdx.y;          // batch
    const int wv = threadIdx.x >> 6;
    const int lane = threadIdx.x & 63;

    const float* pb = partials + (size_t)b * 16 * PSTR;

    // L: lanes load lsum[lane&15] (4 replicated groups), butterfly 4 stages
    float L = pb[(size_t)(lane & 15) * PSTR];
#pragma unroll
    for (int off = 1; off < 16; off <<= 1) L += __shfl_xor(L, off);

    // sum 4 chunks for this wave, independent chains
    const int c0 = wv * 4;
    const int idx = s * 64 + lane;     // f32x4 index within acc[1024]
    f32x4 a0 = ((const f32x4*)(pb + (size_t)(c0 + 0) * PSTR + 8))[idx];
    f32x4 a1 = ((const f32x4*)(pb + (size_t)(c0 + 1) * PSTR + 8))[idx];
    f32x4 a2 = ((const f32x4*)(pb + (size_t)(c0 + 2) * PSTR + 8))[idx];
    f32x4 a3 = ((const f32x4*)(pb + (size_t)(c0 + 3) * PSTR + 8))[idx];
    f32x4 o = (a0 + a1) + (a2 + a3);

    __shared__ f32x4 red[4][64];
    red[wv][lane] = o;
    __syncthreads();

    if (wv == 0) {
        f32x4 t = (red[0][lane] + red[1][lane]) + (red[2][lane] + red[3][lane]);
        f32x4 r = t * (1.f / L);
        ((f32x4*)out)[b * 256 + s * 64 + lane] = r;
    }
}

// Fallback for other C: serial per-batch combine.
__global__ __launch_bounds__(256) void combine_generic(
    const float* __restrict__ partials, float* __restrict__ out, int C)
{
    const int b = blockIdx.x;
    const int tid = threadIdx.x;
    float L = 0.f;
    f32x4 o = {0.f, 0.f, 0.f, 0.f};
    for (int c = 0; c < C; ++c) {
        const float* p = partials + (size_t)(b * C + c) * PSTR;
        L += p[0];
        o += ((const f32x4*)(p + 8))[tid];
    }
    f32x4 r = o * (1.f / L);
    ((f32x4*)out)[b * 256 + tid] = r;
}

extern "C" void kernel_launch(void* const* d_in, const int* in_sizes, int n_in,
                              void* d_out, int out_size, void* d_ws, size_t ws_size,
                              hipStream_t stream) {
    const float* x    = (const float*)d_in[0];   // [B,T,D]
    const float* w    = (const float*)d_in[1];   // [D,1]
    const float* bias = (const float*)d_in[2];   // [T,1]
    float* out = (float*)d_out;

    int D = in_sizes[1];            // 1024
    int T = in_sizes[2];            // 2048
    int nrows = in_sizes[0] / D;    // B*T
    int B = nrows / T;              // 32

    int C = T / 128;                // 128 rows per block -> 16 per wave; C=16

    float* partials = (float*)d_ws;

    fused_main<<<dim3(C, B), 512, 0, stream>>>(x, w, bias, partials, T, C);
    if (C == 16)
        combine16_kernel<<<dim3(4, B), 256, 0, stream>>>(partials, out);
    else
        combine_generic<<<B, 256, 0, stream>>>(partials, out, C);
}